// Round 4
// baseline (392.386 us; speedup 1.0000x reference)
//
#include <hip/hip_runtime.h>
#include <math.h>

#define BB 16
#define CC 64
#define HH 224
#define WW 224
#define HWSZ (HH * WW)          // 50176
#define HW4 (HWSZ / 4)          // 12544
#define W4 (WW / 4)             // 56

// padded feat layout: [plane 2][b 16][prow 230][pcol 240] floats, f4-addressed.
// prow = h+3 (3 zero rows top/bottom), pcol = col+8 (8 zero cols left, 8 right).
#define PROWS (HH + 6)          // 230
#define PW4 60                  // 240 floats per padded row / 4
#define PPLANE (PROWS * PW4)    // 13800 f4 per (plane,batch)
#define NPADC 1256              // zero pad cells (f4) per batch: 6*60 + 224*4
#define NPADT (BB * NPADC)      // 20096 pad-zeroing duties

typedef float f32x4 __attribute__((ext_vector_type(4)));

// ---------------- kernel A: channel mean+max reduce -> padded feat ----------
#define TA 256
#define NPIX (BB * HW4)         // 200704 float4 pixels
#define NBLKA (NPIX / TA)       // 784 blocks

__global__ __launch_bounds__(TA) void reduce_kernel(const float* __restrict__ x,
                                                    float* __restrict__ feat) {
    const int idx = blockIdx.x * TA + threadIdx.x;   // 0 .. NPIX-1
    const int b   = idx / HW4;
    const int p   = idx - b * HW4;
    const f32x4* xp = reinterpret_cast<const f32x4*>(x) + (size_t)b * (CC * HW4) + p;

    f32x4 s = {0.f, 0.f, 0.f, 0.f};
    f32x4 m = {-INFINITY, -INFINITY, -INFINITY, -INFINITY};
#pragma unroll 16
    for (int c = 0; c < CC; ++c) {
        f32x4 u = xp[(size_t)c * HW4];
        s += u;
        m[0] = fmaxf(m[0], u[0]); m[1] = fmaxf(m[1], u[1]);
        m[2] = fmaxf(m[2], u[2]); m[3] = fmaxf(m[3], u[3]);
    }

    f32x4* fa4 = reinterpret_cast<f32x4*>(feat);
    f32x4* fm4 = fa4 + (size_t)BB * PPLANE;

    const int h  = p / W4;
    const int w4 = p - h * W4;
    const size_t o = (size_t)(b * PROWS + (h + 3)) * PW4 + (w4 + 2);
    fa4[o] = s * (1.0f / 64.0f);
    fm4[o] = m;

    // spare duty: zero the pad borders (3 rows top/bottom, 2 f4 left/right)
    if (idx < NPADT) {
        const int pb = idx / NPADC;
        int r = idx - pb * NPADC;
        int prow, c4;
        if (r < 360) {                       // full pad rows (0..2, 227..229)
            int rr = r / 60;
            c4 = r - rr * 60;
            prow = (rr < 3) ? rr : 224 + rr; // 3,4,5 -> 227,228,229
        } else {                             // side pads of interior rows
            int r2 = r - 360;
            int rw = r2 >> 2;
            int k  = r2 & 3;
            prow = rw + 3;
            c4 = (k < 2) ? k : 56 + k;       // {0,1,58,59}
        }
        const size_t oz = (size_t)(pb * PROWS + prow) * PW4 + c4;
        f32x4 z = {0.f, 0.f, 0.f, 0.f};
        fa4[oz] = z;
        fm4[oz] = z;
    }
}

// ---------------- kernel C: register-blocked 7x7 conv + sigmoid -------------
// One thread -> 8 consecutive outputs. No LDS, no barriers, no border masking
// (pads are zero). feat reads are L2/LLC hits (7 MB, read ~7x = 50 MB of L2).
#define TCN 256
#define SEGS (WW / 8)           // 28 segments per row
#define NTHC (BB * HH * SEGS)   // 100352 threads
#define NBLKC (NTHC / TCN)      // 392 blocks

__global__ __launch_bounds__(TCN) void conv_kernel(const float* __restrict__ feat,
                                                   const float* __restrict__ cw,
                                                   const float* __restrict__ cb,
                                                   float* __restrict__ gate) {
    const int tid = blockIdx.x * TCN + threadIdx.x;  // 0 .. NTHC-1
    const int b   = tid / (HH * SEGS);
    const int r   = tid - b * (HH * SEGS);
    const int row = r / SEGS;
    const int seg = r - row * SEGS;
    const int w0  = seg * 8;

    // weights: uniform indices -> scalar loads (SGPR-resident)
    float wa[49], wb[49];
#pragma unroll
    for (int i = 0; i < 49; ++i) { wa[i] = cw[i]; wb[i] = cw[49 + i]; }
    const float bias = cb[0];

    const f32x4* fab = reinterpret_cast<const f32x4*>(feat) + (size_t)b * PPLANE;
    const f32x4* fmb = fab + (size_t)BB * PPLANE;

    float acc[8];
#pragma unroll
    for (int j = 0; j < 8; ++j) acc[j] = bias;

#pragma unroll
    for (int kh = 0; kh < 7; ++kh) {
        // window: padded cols [w0+4, w0+20) == data cols [w0-4, w0+12)
        const int bi = (row + kh) * PW4 + seg * 2 + 1;
        float fA[16], fM[16];
#pragma unroll
        for (int q = 0; q < 4; ++q) {
            f32x4 a = fab[bi + q];
            f32x4 mm = fmb[bi + q];
#pragma unroll
            for (int e = 0; e < 4; ++e) { fA[q * 4 + e] = a[e]; fM[q * 4 + e] = mm[e]; }
        }
#pragma unroll
        for (int kw = 0; kw < 7; ++kw) {
            const float w1 = wa[kh * 7 + kw];
            const float w2 = wb[kh * 7 + kw];
#pragma unroll
            for (int j = 0; j < 8; ++j) {
                acc[j] = fmaf(fA[1 + kw + j], w1, acc[j]);
                acc[j] = fmaf(fM[1 + kw + j], w2, acc[j]);
            }
        }
    }

    f32x4 g0, g1;
#pragma unroll
    for (int j = 0; j < 4; ++j) g0[j] = 1.0f / (1.0f + expf(-acc[j]));
#pragma unroll
    for (int j = 0; j < 4; ++j) g1[j] = 1.0f / (1.0f + expf(-acc[4 + j]));

    f32x4* gb = reinterpret_cast<f32x4*>(gate) + ((size_t)b * HWSZ + (size_t)row * WW + w0) / 4;
    gb[0] = g0;
    gb[1] = g1;
}

// ---------------- kernel M: out = x * gate (pure streamer) ------------------
#define TM 256
#define CSPL 4                  // channel-split: 4 groups of 16 channels
#define CPG (CC / CSPL)         // 16
#define CHUNKS (HW4 / TM)       // 49 pixel chunks per batch
#define NBLKM (BB * CSPL * CHUNKS)  // 3136 blocks (~12 blocks/CU)

__global__ __launch_bounds__(TM) void mul_kernel(const float* __restrict__ x,
                                                 const float* __restrict__ gate,
                                                 float* __restrict__ out) {
    const int blk   = blockIdx.x;
    const int chunk = blk % CHUNKS;
    const int cg    = (blk / CHUNKS) % CSPL;
    const int b     = blk / (CHUNKS * CSPL);
    const int p     = chunk * TM + threadIdx.x;      // float4 pixel in plane

    const f32x4 g = reinterpret_cast<const f32x4*>(gate)[(size_t)b * HW4 + p];

    const size_t base = ((size_t)b * CC + cg * CPG) * HW4 + p;
    const f32x4* xp = reinterpret_cast<const f32x4*>(x) + base;
    f32x4*       op = reinterpret_cast<f32x4*>(out) + base;
#pragma unroll
    for (int c = 0; c < CPG; ++c) {
        f32x4 v = xp[(size_t)c * HW4];
        v *= g;
        op[(size_t)c * HW4] = v;     // normal store (nt-hypothesis test)
    }
}

extern "C" void kernel_launch(void* const* d_in, const int* in_sizes, int n_in,
                              void* d_out, int out_size, void* d_ws, size_t ws_size,
                              hipStream_t stream) {
    const float* x  = (const float*)d_in[0];   // [16,64,224,224]
    const float* cw = (const float*)d_in[1];   // [1,2,7,7]
    const float* cb = (const float*)d_in[2];   // [1]
    float* out  = (float*)d_out;
    float* feat = (float*)d_ws;                          // padded planes, 7.07 MB
    float* gate = feat + (size_t)2 * BB * PPLANE * 4;    // flat [16][224][224], 3.2 MB

    reduce_kernel<<<NBLKA, TA, 0, stream>>>(x, feat);
    conv_kernel<<<NBLKC, TCN, 0, stream>>>(feat, cw, cb, gate);
    mul_kernel<<<NBLKM, TM, 0, stream>>>(x, gate, out);
}

// Round 5
// 392.210 us; speedup vs baseline: 1.0005x; 1.0005x over previous
//
#include <hip/hip_runtime.h>
#include <math.h>

#define BB 16
#define CC 64
#define HH 224
#define WW 224
#define HWSZ (HH * WW)          // 50176
#define HW4 (HWSZ / 4)          // 12544
#define W4 (WW / 4)             // 56

// padded feat layout: [plane 2][b 16][prow 230][pcol 240] floats, f4-addressed.
// prow = h+3 (3 zero rows top/bottom), pcol = col+8 (8 zero cols left/right).
#define PROWS (HH + 6)          // 230
#define PW4 60                  // 240 floats / 4
#define PPLANE (PROWS * PW4)    // 13800 f4 per (plane,batch)
#define NPADC 1256              // zero pad cells (f4) per batch: 6*60 + 224*4
#define NPADT (BB * NPADC)      // 20096 pad-zeroing duties

typedef float f32x4 __attribute__((ext_vector_type(4)));

// ---------------- kernel A: channel mean+max reduce (4-way split) -----------
// Block = 256 threads = 64 consecutive f4 pixels x 4 channel-groups of 16.
// Partials combined via LDS. 3136 main blocks -> full occupancy (32 waves/CU),
// 4x the concurrent pixel streams of the thread-per-pixel version.
#define TA 256
#define NPIX (BB * HW4)         // 200704 f4 pixels
#define PIXBLK 64
#define NBLKA_MAIN (NPIX / PIXBLK)            // 3136 (HW4 % 64 == 0)
#define NBLKA_PAD ((NPADT + TA - 1) / TA)     // 79
#define NBLKA (NBLKA_MAIN + NBLKA_PAD)

__global__ __launch_bounds__(TA) void reduce_kernel(const float* __restrict__ x,
                                                    float* __restrict__ feat) {
    __shared__ f32x4 sS[4][PIXBLK];
    __shared__ f32x4 sM[4][PIXBLK];

    const int blk = blockIdx.x;
    const int t   = threadIdx.x;
    f32x4* fa4 = reinterpret_cast<f32x4*>(feat);
    f32x4* fm4 = fa4 + (size_t)BB * PPLANE;

    if (blk < NBLKA_MAIN) {
        const int P0    = blk * PIXBLK;          // global f4 pixel base
        const int bimg  = P0 / HW4;
        const int pbase = P0 - bimg * HW4;
        const int lane  = t & 63;
        const int cg    = t >> 6;                // 0..3, 16 channels each
        const int p     = pbase + lane;

        const f32x4* xp = reinterpret_cast<const f32x4*>(x)
                        + ((size_t)(bimg * CC + cg * 16)) * HW4 + p;
        f32x4 s = {0.f, 0.f, 0.f, 0.f};
        f32x4 m = {-INFINITY, -INFINITY, -INFINITY, -INFINITY};
#pragma unroll 8
        for (int c = 0; c < 16; ++c) {
            f32x4 u = xp[(size_t)c * HW4];
            s += u;
            m[0] = fmaxf(m[0], u[0]); m[1] = fmaxf(m[1], u[1]);
            m[2] = fmaxf(m[2], u[2]); m[3] = fmaxf(m[3], u[3]);
        }
        sS[cg][lane] = s;
        sM[cg][lane] = m;
        __syncthreads();

        if (t < PIXBLK) {                        // combine sums -> avg plane
            f32x4 r = sS[0][t] + sS[1][t] + sS[2][t] + sS[3][t];
            const int pp = pbase + t;
            const int h  = pp / W4;
            const int w4 = pp - h * W4;
            fa4[(size_t)(bimg * PROWS + h + 3) * PW4 + (w4 + 2)] = r * (1.0f / 64.0f);
        } else if (t < 2 * PIXBLK) {             // combine maxes -> max plane
            const int l = t - PIXBLK;
            f32x4 a = sM[0][l], b2 = sM[1][l], c2 = sM[2][l], d = sM[3][l];
            f32x4 r;
#pragma unroll
            for (int e = 0; e < 4; ++e)
                r[e] = fmaxf(fmaxf(a[e], b2[e]), fmaxf(c2[e], d[e]));
            const int pp = pbase + l;
            const int h  = pp / W4;
            const int w4 = pp - h * W4;
            fm4[(size_t)(bimg * PROWS + h + 3) * PW4 + (w4 + 2)] = r;
        }
    } else {
        // pad-zero duty blocks
        const int idx = (blk - NBLKA_MAIN) * TA + t;
        if (idx < NPADT) {
            const int pb = idx / NPADC;
            int r = idx - pb * NPADC;
            int prow, c4;
            if (r < 360) {                       // full pad rows (0..2, 227..229)
                int rr = r / 60;
                c4 = r - rr * 60;
                prow = (rr < 3) ? rr : 224 + rr;
            } else {                             // side pads of interior rows
                int r2 = r - 360;
                int rw = r2 >> 2;
                int k  = r2 & 3;
                prow = rw + 3;
                c4 = (k < 2) ? k : 56 + k;       // {0,1,58,59}
            }
            const size_t oz = (size_t)(pb * PROWS + prow) * PW4 + c4;
            f32x4 z = {0.f, 0.f, 0.f, 0.f};
            fa4[oz] = z;
            fm4[oz] = z;
        }
    }
}

// ---------------- kernel B: register conv + multiply, fused -----------------
// Each thread: 7x7 conv for its own f4 pixel (4 outputs) from padded feat
// (L2/IC-hit), weights via LDS broadcast, then multiplies 32 channels of x by
// the in-register gate. No gate round-trip, one trivial barrier.
#define TB 256
#define BSPL 2                  // channel split: 2 groups of 32
#define CPG2 (CC / BSPL)        // 32
#define CHB (HW4 / TB)          // 49 pixel chunks per batch
#define NBLKB (BB * BSPL * CHB) // 1568 blocks -> ~24.5 waves/CU

__global__ __launch_bounds__(TB) void conv_mul_kernel(const float* __restrict__ x,
                                                      const float* __restrict__ feat,
                                                      const float* __restrict__ cw,
                                                      const float* __restrict__ cb,
                                                      float* __restrict__ out) {
    __shared__ float ws[98];

    const int blk = blockIdx.x;
    const int t   = threadIdx.x;
    if (t < 98) ws[t] = cw[t];

    const int chunk = blk % CHB;
    const int half  = (blk / CHB) % BSPL;
    const int b     = blk / (CHB * BSPL);
    const int p     = chunk * TB + t;            // f4 pixel in plane
    const int row   = p / W4;
    const int c4    = p - row * W4;
    __syncthreads();

    const f32x4* fab = reinterpret_cast<const f32x4*>(feat) + (size_t)b * PPLANE;
    const f32x4* fmb = fab + (size_t)BB * PPLANE;
    const float bias = cb[0];

    float acc[4] = {bias, bias, bias, bias};
#pragma unroll 1                                 // keep VGPR low: one kh row live
    for (int kh = 0; kh < 7; ++kh) {
        const int bi = (row + kh) * PW4 + c4 + 1;   // 12-float window base
        float fA[12], fM[12];
#pragma unroll
        for (int q = 0; q < 3; ++q) {
            f32x4 a = fab[bi + q];
            f32x4 mm = fmb[bi + q];
#pragma unroll
            for (int e = 0; e < 4; ++e) { fA[q * 4 + e] = a[e]; fM[q * 4 + e] = mm[e]; }
        }
#pragma unroll
        for (int kw = 0; kw < 7; ++kw) {
            const float w1 = ws[kh * 7 + kw];
            const float w2 = ws[49 + kh * 7 + kw];
#pragma unroll
            for (int j = 0; j < 4; ++j) {
                acc[j] = fmaf(fA[1 + kw + j], w1, acc[j]);
                acc[j] = fmaf(fM[1 + kw + j], w2, acc[j]);
            }
        }
    }

    f32x4 g;
#pragma unroll
    for (int j = 0; j < 4; ++j) g[j] = 1.0f / (1.0f + expf(-acc[j]));

    const size_t base = ((size_t)(b * CC + half * CPG2)) * HW4 + p;
    const f32x4* xp = reinterpret_cast<const f32x4*>(x) + base;
    f32x4*       op = reinterpret_cast<f32x4*>(out) + base;
#pragma unroll 8
    for (int c = 0; c < CPG2; ++c) {
        f32x4 v = xp[(size_t)c * HW4];
        v *= g;
        op[(size_t)c * HW4] = v;
    }
}

extern "C" void kernel_launch(void* const* d_in, const int* in_sizes, int n_in,
                              void* d_out, int out_size, void* d_ws, size_t ws_size,
                              hipStream_t stream) {
    const float* x  = (const float*)d_in[0];   // [16,64,224,224]
    const float* cw = (const float*)d_in[1];   // [1,2,7,7]
    const float* cb = (const float*)d_in[2];   // [1]
    float* out  = (float*)d_out;
    float* feat = (float*)d_ws;                // padded planes, 7.07 MB

    reduce_kernel<<<NBLKA, TA, 0, stream>>>(x, feat);
    conv_mul_kernel<<<NBLKB, TB, 0, stream>>>(x, feat, cw, cb, out);
}